// Round 2
// baseline (18298.314 us; speedup 1.0000x reference)
//
#include <hip/hip_runtime.h>
#include <stdint.h>
#include <math.h>

// Problem constants (match reference)
#define BB 128
#define NN 2048
#define DD 2
#define ROWLEN (2 + NN * DD + 5)   // 4103
#define SIGMA_C 0.001f
#define HALF_CNT 262144u           // B*N*D / 2

// ---------------------------------------------------------------------------
// R1 post-mortem: ext_vector activations (v16f/v32f) are single SSA values
// needing CONTIGUOUS 16/32-register tuples. 96 tuple-registers of live state
// can't be colored, so the allocator dumped whole tuples to scratch every
// step (12.3 GB HBM traffic, runtime == spill time). This version:
//   - named scalar floats (macro-expanded) — no tuple constraint
//   - h1/h2 dropped after fwd use, recomputed bit-identically in bwd
//   - g2/g1 fused into incremental a[k] accumulation (same fmaf chain order)
//   - tilt products hoisted (same arithmetic, select moved after the fmafs)
// Peak liveness ~80 regs -> fits the allocator's 6-wave/84-VGPR target.
// All op sequences bit-identical to the previous passing kernel.
// ---------------------------------------------------------------------------

// repetition macros: A-suffix for outer loops, B-suffix for inner loops
// (cpp will not re-expand a macro inside itself, so the copies are required)
#define R16A(M) M(0) M(1) M(2) M(3) M(4) M(5) M(6) M(7) M(8) M(9) M(10) M(11) M(12) M(13) M(14) M(15)
#define R32A(M) R16A(M) M(16) M(17) M(18) M(19) M(20) M(21) M(22) M(23) M(24) M(25) M(26) M(27) M(28) M(29) M(30) M(31)
#define R16B(M) M(0) M(1) M(2) M(3) M(4) M(5) M(6) M(7) M(8) M(9) M(10) M(11) M(12) M(13) M(14) M(15)
#define R32B(M) R16B(M) M(16) M(17) M(18) M(19) M(20) M(21) M(22) M(23) M(24) M(25) M(26) M(27) M(28) M(29) M(30) M(31)

#define ELU(z) ((z) > 0.0f ? (z) : (__expf(z) - 1.0f))
// elu derivative from elu output: d = (z>0) ? 1 : exp(z); for z<=0,
// h = exp(z)-1  =>  d = h+1 (bit-matches the original kernel's DFROMH)
#define DFROMH(h) ((h) > 0.0f ? 1.0f : (h) + 1.0f)

__device__ __forceinline__ uint32_t rotl32(uint32_t v, uint32_t r) {
  return (v << r) | (v >> (32u - r));
}

// JAX threefry2x32 (20 rounds), matches jax/_src/prng.py
__device__ __forceinline__ void tf2x32(uint32_t k0, uint32_t k1,
                                       uint32_t x0, uint32_t x1,
                                       uint32_t& o0, uint32_t& o1) {
  uint32_t k2 = k0 ^ k1 ^ 0x1BD11BDAu;
  x0 += k0; x1 += k1;
#define TF_R(r) { x0 += x1; x1 = rotl32(x1, r); x1 ^= x0; }
  TF_R(13) TF_R(15) TF_R(26) TF_R(6)   x0 += k1; x1 += k2 + 1u;
  TF_R(17) TF_R(29) TF_R(16) TF_R(24)  x0 += k2; x1 += k0 + 2u;
  TF_R(13) TF_R(15) TF_R(26) TF_R(6)   x0 += k0; x1 += k1 + 3u;
  TF_R(17) TF_R(29) TF_R(16) TF_R(24)  x0 += k1; x1 += k2 + 4u;
  TF_R(13) TF_R(15) TF_R(26) TF_R(6)   x0 += k2; x1 += k0 + 5u;
#undef TF_R
  o0 = x0; o1 = x1;
}

// XLA f32 ErfInv (Giles 2012 polynomial) — what lax.erf_inv lowers to
__device__ __forceinline__ float erfinv_f32(float x) {
  float w = -log1pf(-(x * x));
  float p;
  if (w < 5.0f) {
    w = w - 2.5f;
    p = 2.81022636e-08f;
    p = fmaf(p, w, 3.43273939e-07f);
    p = fmaf(p, w, -3.5233877e-06f);
    p = fmaf(p, w, -4.39150654e-06f);
    p = fmaf(p, w, 0.00021858087f);
    p = fmaf(p, w, -0.00125372503f);
    p = fmaf(p, w, -0.00417768164f);
    p = fmaf(p, w, 0.246640727f);
    p = fmaf(p, w, 1.50140941f);
  } else {
    w = sqrtf(w) - 3.0f;
    p = -0.000200214257f;
    p = fmaf(p, w, 0.000100950558f);
    p = fmaf(p, w, 0.00134934322f);
    p = fmaf(p, w, -0.00367342844f);
    p = fmaf(p, w, 0.00573950773f);
    p = fmaf(p, w, -0.0076224613f);
    p = fmaf(p, w, 0.00943887047f);
    p = fmaf(p, w, 1.00167406f);
    p = fmaf(p, w, 2.83297682f);
  }
  return p * x;
}

// jax.random.normal for one flat element index f under key (k0,k1)
__device__ __forceinline__ float jax_normal_elem(uint32_t k0, uint32_t k1,
                                                 uint32_t f) {
  uint32_t o0, o1, bits;
  if (f < HALF_CNT) {
    tf2x32(k0, k1, f, f + HALF_CNT, o0, o1);
    bits = o0;
  } else {
    tf2x32(k0, k1, f - HALF_CNT, f, o0, o1);
    bits = o1;
  }
  float u01 = __uint_as_float((bits >> 9) | 0x3f800000u) - 1.0f;
  const float lo = -0.99999994f;           // nextafter(-1, 0) in f32
  float v = fmaxf(lo, fmaf(u01, 2.0f, lo));
  return 1.41421356237309515f * erfinv_f32(v);
}

__global__ __launch_bounds__(256, 2) void phinn_kernel(
    const float* __restrict__ x,
    const float* __restrict__ W1, const float* __restrict__ b1,
    const float* __restrict__ W2, const float* __restrict__ b2,
    const float* __restrict__ W3, const float* __restrict__ b3,
    const float* __restrict__ W4, const float* __restrict__ b4,
    const float* __restrict__ W5, const float* __restrict__ b5,
    const float* __restrict__ Wt,
    const float* __restrict__ dtp, const int* __restrict__ nstepsp,
    float* __restrict__ out) {
  const int tid = blockIdx.x * 256 + threadIdx.x;   // 0 .. B*N-1
  const int bidx = tid >> 11;                        // / N
  const int nidx = tid & (NN - 1);

  const float dt = dtp[0];
  const int nsteps = nstepsp[0];
  const float sqdt = sqrtf(dt);

  const float* xr = x + (size_t)bidx * ROWLEN;
  float tt = xr[0];
  float y0 = xr[2 + nidx * 2 + 0];
  float y1 = xr[2 + nidx * 2 + 1];
  const float tcrit = xr[2 + NN * DD + 0];

  // Hoisted tilt products: same fmafs as the in-loop original, with the
  // pre/post select moved AFTER the arithmetic (bit-identical values).
  {
  }
  const float sp0 = xr[2 + NN * DD + 1];
  const float sp1 = xr[2 + NN * DD + 2];
  const float sq0 = xr[2 + NN * DD + 3];
  const float sq1 = xr[2 + NN * DD + 4];
  const float wt00 = Wt[0], wt01 = Wt[1], wt10 = Wt[2], wt11 = Wt[3];
  const float tp0 = fmaf(sp0, wt00, sp1 * wt01);
  const float tp1 = fmaf(sp0, wt10, sp1 * wt11);
  const float tq0 = fmaf(sq0, wt00, sq1 * wt01);
  const float tq1 = fmaf(sq0, wt10, sq1 * wt11);

  const uint32_t f0 = (uint32_t)(tid << 1);  // flat idx of component 0

  // named scalar activation state (no arrays, no vectors)
#define DECL_F(n) float n;
#define D_H1(j) float h1_##j;
#define D_H2(j) float h2_##j;
#define D_H3(j) float h3_##j;
#define D_H4(j) float h4_##j;
#define D_G3(j) float g3_##j;
#define D_G4(j) float g4_##j;
#define D_A(j)  float a_##j;
  R16A(D_H1)
  R32A(D_H2)
  R32A(D_H3)
  R16A(D_H4)
  R32A(D_G3)
  R16A(D_G4)
  R16A(D_A)

  for (int i = 0; i < nsteps; ++i) {
    // per-step key: fold_in(key(42), i) = threefry((0,42), (0,i))
    // (uniform across threads -> compiler scalarizes to the SALU pipe)
    uint32_t k0, k1;
    tf2x32(0u, 42u, 0u, (uint32_t)i, k0, k1);

    // ---- forward: 2 -> 16 -> 32 -> 32 -> 16 -> 1 ----
    // h1 (dropped after h2; recomputed bit-identically in backward)
#define S_H1(j) { float z = fmaf(W1[2*j+0], y0, fmaf(W1[2*j+1], y1, b1[j])); h1_##j = ELU(z); }
    R16A(S_H1)

    // h2 (dropped after h3; recomputed per-element in backward)
#define MAC_H2(k) z = fmaf(W2[16*J+k], h1_##k, z);
#define S_H2(j) { const int J = j; float z = b2[J]; R16B(MAC_H2) h2_##j = ELU(z); }
    R32A(S_H2)

    // h3 (kept: needed for d3 in backward)
#define MAC_H3(k) z = fmaf(W3[32*J+k], h2_##k, z);
#define S_H3(j) { const int J = j; float z = b3[J]; R32B(MAC_H3) h3_##j = ELU(z); }
    R32A(S_H3)

    // h4 (kept through g4)
#define MAC_H4(k) z = fmaf(W4[32*J+k], h3_##k, z);
#define S_H4(j) { const int J = j; float z = b4[J]; R32B(MAC_H4) h4_##j = ELU(z); }
    R16A(S_H4)

    float z5 = b5[0];
#define MAC_Z5(k) z5 = fmaf(W5[k], h4_##k, z5);
    R16A(MAC_Z5)
    // d softplus = sigmoid
    float g5 = 1.0f / (1.0f + __expf(-z5));

    // ---- backward (input-gradient) ----
#define S_G4(j) g4_##j = W5[j] * g5 * DFROMH(h4_##j);
    R16A(S_G4)

#define MAC_G3(j) s = fmaf(W4[32*j+K], g4_##j, s);
#define S_G3(k) { const int K = k; float s = 0.0f; R16B(MAC_G3) g3_##k = s * DFROMH(h3_##k); }
    R32A(S_G3)

    // recompute h1 from y (identical op sequence -> bit-identical values)
#define S_RH1(j) { float z = fmaf(W1[2*j+0], y0, fmaf(W1[2*j+1], y1, b1[j])); h1_##j = ELU(z); }
    R16A(S_RH1)

    // fused g2 -> a: for each j, produce g2_j (recomputing h2_j bit-exactly),
    // then immediately fold it into a_k = sum_j W2[16j+k]*g2_j.
    // Per-k accumulation order over j is 0..31, identical to the original
    // g1 fmaf chain.
#define Z_A(k) a_##k = 0.0f;
    R16A(Z_A)
#define MAC_T(i) tsum = fmaf(W3[32*i+J], g3_##i, tsum);
#define MAC_Z2(k) z2 = fmaf(W2[16*J+k], h1_##k, z2);
#define MAC_A(k) a_##k = fmaf(W2[16*J+k], g2j, a_##k);
#define S_G2(j) { const int J = j; \
      float tsum = 0.0f; R32B(MAC_T) \
      float z2 = b2[J]; R16B(MAC_Z2) \
      float h2r = ELU(z2); \
      float g2j = tsum * DFROMH(h2r); \
      R16B(MAC_A) }
    R32A(S_G2)

    // g1 and input-gradient, fused (same fmaf chain order as original)
    float gy0 = 0.0f, gy1 = 0.0f;
#define MAC_GY(j) { float g1j = a_##j * DFROMH(h1_##j); \
      gy0 = fmaf(W1[2*j+0], g1j, gy0); \
      gy1 = fmaf(W1[2*j+1], g1j, gy1); }
    R16A(MAC_GY)

    // ---- tilt (hoisted products, select only) ----
    bool pre = tt < tcrit;
    float tilt0 = pre ? tp0 : tq0;
    float tilt1 = pre ? tp1 : tq1;

    // ---- noise (exact JAX threefry normal) ----
    float nz0 = jax_normal_elem(k0, k1, f0);
    float nz1 = jax_normal_elem(k0, k1, f0 + 1u);

    // ---- Euler-Maruyama update ----
    float drift0 = -(gy0 + tilt0);
    float drift1 = -(gy1 + tilt1);
    y0 = y0 + drift0 * dt + SIGMA_C * (nz0 * sqdt);
    y1 = y1 + drift1 * dt + SIGMA_C * (nz1 * sqdt);
    tt += dt;
  }

  out[(size_t)tid * 2 + 0] = y0;
  out[(size_t)tid * 2 + 1] = y1;
}

extern "C" void kernel_launch(void* const* d_in, const int* in_sizes, int n_in,
                              void* d_out, int out_size, void* d_ws,
                              size_t ws_size, hipStream_t stream) {
  const float* x  = (const float*)d_in[0];
  const float* W1 = (const float*)d_in[1];
  const float* b1 = (const float*)d_in[2];
  const float* W2 = (const float*)d_in[3];
  const float* b2 = (const float*)d_in[4];
  const float* W3 = (const float*)d_in[5];
  const float* b3 = (const float*)d_in[6];
  const float* W4 = (const float*)d_in[7];
  const float* b4 = (const float*)d_in[8];
  const float* W5 = (const float*)d_in[9];
  const float* b5 = (const float*)d_in[10];
  const float* Wt = (const float*)d_in[11];
  const float* dt = (const float*)d_in[12];
  const int* nsteps = (const int*)d_in[13];
  float* out = (float*)d_out;

  dim3 grid((BB * NN) / 256);
  dim3 block(256);
  hipLaunchKernelGGL(phinn_kernel, grid, block, 0, stream,
                     x, W1, b1, W2, b2, W3, b3, W4, b4, W5, b5, Wt, dt, nsteps,
                     out);
}

// Round 3
// 6390.567 us; speedup vs baseline: 2.8633x; 2.8633x over previous
//
#include <hip/hip_runtime.h>
#include <stdint.h>
#include <math.h>

// Problem constants (match reference)
#define BB 128
#define NN 2048
#define DD 2
#define ROWLEN (2 + NN * DD + 5)   // 4103
#define SIGMA_C 0.001f
#define HALF_CNT 262144u           // B*N*D / 2

// ---------------------------------------------------------------------------
// R2 post-mortem: scalarization cut spill 13x but VGPR=88 vs g3-phase peak
// liveness ~92-96 (h3:32 + g4:16 + g3:32 + misc) -> ~4 floats/step still
// round-tripped through scratch (FETCH 712MB / WRITE 218MB), occupancy 21%,
// latency-bound at VALUBusy 50%. This version moves h3 to LDS:
//   - fwd writes h3_j to sh3[j][tid] as produced (h3 regs die after h4)
//   - bwd g3 loop reads h3 back one element at a time (conflict-free: lane
//     stride 4B, 2-way aliasing is free on 32-bank LDS)
//   - asm "memory" clobber between fwd/bwd stops store-to-load forwarding
//     from resurrecting the h3 registers
//   - threefry key computed AFTER the MLP (k0/k1 not live across it)
// g3-phase liveness drops to ~50; overall peak ~78 < 88 budget -> no scratch.
// All arithmetic sequences bit-identical to the passing R2 kernel.
// ---------------------------------------------------------------------------

// repetition macros: A-suffix for outer loops, B-suffix for inner loops
// (cpp will not re-expand a macro inside itself, so the copies are required)
#define R16A(M) M(0) M(1) M(2) M(3) M(4) M(5) M(6) M(7) M(8) M(9) M(10) M(11) M(12) M(13) M(14) M(15)
#define R32A(M) R16A(M) M(16) M(17) M(18) M(19) M(20) M(21) M(22) M(23) M(24) M(25) M(26) M(27) M(28) M(29) M(30) M(31)
#define R16B(M) M(0) M(1) M(2) M(3) M(4) M(5) M(6) M(7) M(8) M(9) M(10) M(11) M(12) M(13) M(14) M(15)
#define R32B(M) R16B(M) M(16) M(17) M(18) M(19) M(20) M(21) M(22) M(23) M(24) M(25) M(26) M(27) M(28) M(29) M(30) M(31)

#define ELU(z) ((z) > 0.0f ? (z) : (__expf(z) - 1.0f))
// elu derivative from elu output: d = (z>0) ? 1 : exp(z); for z<=0,
// h = exp(z)-1  =>  d = h+1 (bit-matches prior kernels' DFROMH)
#define DFROMH(h) ((h) > 0.0f ? 1.0f : (h) + 1.0f)

__device__ __forceinline__ uint32_t rotl32(uint32_t v, uint32_t r) {
  return (v << r) | (v >> (32u - r));
}

// JAX threefry2x32 (20 rounds), matches jax/_src/prng.py
__device__ __forceinline__ void tf2x32(uint32_t k0, uint32_t k1,
                                       uint32_t x0, uint32_t x1,
                                       uint32_t& o0, uint32_t& o1) {
  uint32_t k2 = k0 ^ k1 ^ 0x1BD11BDAu;
  x0 += k0; x1 += k1;
#define TF_R(r) { x0 += x1; x1 = rotl32(x1, r); x1 ^= x0; }
  TF_R(13) TF_R(15) TF_R(26) TF_R(6)   x0 += k1; x1 += k2 + 1u;
  TF_R(17) TF_R(29) TF_R(16) TF_R(24)  x0 += k2; x1 += k0 + 2u;
  TF_R(13) TF_R(15) TF_R(26) TF_R(6)   x0 += k0; x1 += k1 + 3u;
  TF_R(17) TF_R(29) TF_R(16) TF_R(24)  x0 += k1; x1 += k2 + 4u;
  TF_R(13) TF_R(15) TF_R(26) TF_R(6)   x0 += k2; x1 += k0 + 5u;
#undef TF_R
  o0 = x0; o1 = x1;
}

// XLA f32 ErfInv (Giles 2012 polynomial) — what lax.erf_inv lowers to
__device__ __forceinline__ float erfinv_f32(float x) {
  float w = -log1pf(-(x * x));
  float p;
  if (w < 5.0f) {
    w = w - 2.5f;
    p = 2.81022636e-08f;
    p = fmaf(p, w, 3.43273939e-07f);
    p = fmaf(p, w, -3.5233877e-06f);
    p = fmaf(p, w, -4.39150654e-06f);
    p = fmaf(p, w, 0.00021858087f);
    p = fmaf(p, w, -0.00125372503f);
    p = fmaf(p, w, -0.00417768164f);
    p = fmaf(p, w, 0.246640727f);
    p = fmaf(p, w, 1.50140941f);
  } else {
    w = sqrtf(w) - 3.0f;
    p = -0.000200214257f;
    p = fmaf(p, w, 0.000100950558f);
    p = fmaf(p, w, 0.00134934322f);
    p = fmaf(p, w, -0.00367342844f);
    p = fmaf(p, w, 0.00573950773f);
    p = fmaf(p, w, -0.0076224613f);
    p = fmaf(p, w, 0.00943887047f);
    p = fmaf(p, w, 1.00167406f);
    p = fmaf(p, w, 2.83297682f);
  }
  return p * x;
}

// jax.random.normal for one flat element index f under key (k0,k1)
__device__ __forceinline__ float jax_normal_elem(uint32_t k0, uint32_t k1,
                                                 uint32_t f) {
  uint32_t o0, o1, bits;
  if (f < HALF_CNT) {
    tf2x32(k0, k1, f, f + HALF_CNT, o0, o1);
    bits = o0;
  } else {
    tf2x32(k0, k1, f - HALF_CNT, f, o0, o1);
    bits = o1;
  }
  float u01 = __uint_as_float((bits >> 9) | 0x3f800000u) - 1.0f;
  const float lo = -0.99999994f;           // nextafter(-1, 0) in f32
  float v = fmaxf(lo, fmaf(u01, 2.0f, lo));
  return 1.41421356237309515f * erfinv_f32(v);
}

__global__ __launch_bounds__(256, 2) void phinn_kernel(
    const float* __restrict__ x,
    const float* __restrict__ W1, const float* __restrict__ b1,
    const float* __restrict__ W2, const float* __restrict__ b2,
    const float* __restrict__ W3, const float* __restrict__ b3,
    const float* __restrict__ W4, const float* __restrict__ b4,
    const float* __restrict__ W5, const float* __restrict__ b5,
    const float* __restrict__ Wt,
    const float* __restrict__ dtp, const int* __restrict__ nstepsp,
    float* __restrict__ out) {
  const int tx = threadIdx.x;
  const int tid = blockIdx.x * 256 + tx;             // 0 .. B*N-1
  const int bidx = tid >> 11;                        // / N
  const int nidx = tid & (NN - 1);

  // h3 stash: lane stride 4B -> banks perfect (2-way aliasing is free).
  // 32KB/block; 4 blocks/CU x 32KB = 128KB <= 160KB, so full residency.
  __shared__ float sh3[32][256];

  const float dt = dtp[0];
  const int nsteps = nstepsp[0];
  const float sqdt = sqrtf(dt);

  const float* xr = x + (size_t)bidx * ROWLEN;
  float tt = xr[0];
  float y0 = xr[2 + nidx * 2 + 0];
  float y1 = xr[2 + nidx * 2 + 1];
  const float tcrit = xr[2 + NN * DD + 0];

  // Hoisted tilt products: same fmafs as the in-loop original, with the
  // pre/post select moved AFTER the arithmetic (bit-identical values).
  const float sp0 = xr[2 + NN * DD + 1];
  const float sp1 = xr[2 + NN * DD + 2];
  const float sq0 = xr[2 + NN * DD + 3];
  const float sq1 = xr[2 + NN * DD + 4];
  const float wt00 = Wt[0], wt01 = Wt[1], wt10 = Wt[2], wt11 = Wt[3];
  const float tp0 = fmaf(sp0, wt00, sp1 * wt01);
  const float tp1 = fmaf(sp0, wt10, sp1 * wt11);
  const float tq0 = fmaf(sq0, wt00, sq1 * wt01);
  const float tq1 = fmaf(sq0, wt10, sq1 * wt11);

  const uint32_t f0 = (uint32_t)(tid << 1);  // flat idx of component 0

  // named scalar activation state (no arrays, no vectors)
#define D_H1(j) float h1_##j;
#define D_H2(j) float h2_##j;
#define D_H3(j) float h3_##j;
#define D_H4(j) float h4_##j;
#define D_G3(j) float g3_##j;
#define D_G4(j) float g4_##j;
#define D_A(j)  float a_##j;
  R16A(D_H1)
  R32A(D_H2)
  R32A(D_H3)
  R16A(D_H4)
  R32A(D_G3)
  R16A(D_G4)
  R16A(D_A)

  for (int i = 0; i < nsteps; ++i) {
    // ---- forward: 2 -> 16 -> 32 -> 32 -> 16 -> 1 ----
    // h1 (dropped after h2; recomputed bit-identically in backward)
#define S_H1(j) { float z = fmaf(W1[2*j+0], y0, fmaf(W1[2*j+1], y1, b1[j])); h1_##j = ELU(z); }
    R16A(S_H1)

    // h2 (dropped after h3; recomputed per-element in backward)
#define MAC_H2(k) z = fmaf(W2[16*J+k], h1_##k, z);
#define S_H2(j) { const int J = j; float z = b2[J]; R16B(MAC_H2) h2_##j = ELU(z); }
    R32A(S_H2)

    // h3: stash to LDS as produced; registers stay live only through h4
#define MAC_H3(k) z = fmaf(W3[32*J+k], h2_##k, z);
#define S_H3(j) { const int J = j; float z = b3[J]; R32B(MAC_H3) h3_##j = ELU(z); sh3[J][tx] = h3_##j; }
    R32A(S_H3)

    // h4 (kept through g4)
#define MAC_H4(k) z = fmaf(W4[32*J+k], h3_##k, z);
#define S_H4(j) { const int J = j; float z = b4[J]; R32B(MAC_H4) h4_##j = ELU(z); }
    R16A(S_H4)

    float z5 = b5[0];
#define MAC_Z5(k) z5 = fmaf(W5[k], h4_##k, z5);
    R16A(MAC_Z5)
    // d softplus = sigmoid
    float g5 = 1.0f / (1.0f + __expf(-z5));

    // ---- backward (input-gradient) ----
#define S_G4(j) g4_##j = W5[j] * g5 * DFROMH(h4_##j);
    R16A(S_G4)

    // stop store-to-load forwarding from resurrecting the h3 registers
    asm volatile("" ::: "memory");

    // g3: h3 re-read from LDS one element at a time (h3 regs are dead)
#define MAC_G3(j) s = fmaf(W4[32*j+K], g4_##j, s);
#define S_G3(k) { const int K = k; float s = 0.0f; R16B(MAC_G3) \
      float h3k = sh3[K][tx]; g3_##k = s * DFROMH(h3k); }
    R32A(S_G3)

    // recompute h1 from y (identical op sequence -> bit-identical values)
#define S_RH1(j) { float z = fmaf(W1[2*j+0], y0, fmaf(W1[2*j+1], y1, b1[j])); h1_##j = ELU(z); }
    R16A(S_RH1)

    // fused g2 -> a: for each j, produce g2_j (recomputing h2_j bit-exactly),
    // then immediately fold it into a_k = sum_j W2[16j+k]*g2_j.
    // Per-k accumulation order over j is 0..31, identical to the original
    // g1 fmaf chain.
#define Z_A(k) a_##k = 0.0f;
    R16A(Z_A)
#define MAC_T(i) tsum = fmaf(W3[32*i+J], g3_##i, tsum);
#define MAC_Z2(k) z2 = fmaf(W2[16*J+k], h1_##k, z2);
#define MAC_A(k) a_##k = fmaf(W2[16*J+k], g2j, a_##k);
#define S_G2(j) { const int J = j; \
      float tsum = 0.0f; R32B(MAC_T) \
      float z2 = b2[J]; R16B(MAC_Z2) \
      float h2r = ELU(z2); \
      float g2j = tsum * DFROMH(h2r); \
      R16B(MAC_A) }
    R32A(S_G2)

    // g1 and input-gradient, fused (same fmaf chain order as original)
    float gy0 = 0.0f, gy1 = 0.0f;
#define MAC_GY(j) { float g1j = a_##j * DFROMH(h1_##j); \
      gy0 = fmaf(W1[2*j+0], g1j, gy0); \
      gy1 = fmaf(W1[2*j+1], g1j, gy1); }
    R16A(MAC_GY)

    // ---- tilt (hoisted products, select only) ----
    bool pre = tt < tcrit;
    float tilt0 = pre ? tp0 : tq0;
    float tilt1 = pre ? tp1 : tq1;

    // ---- per-step key, computed only now so k0/k1 aren't live in the MLP
    // fold_in(key(42), i) = threefry((0,42), (0,i)); uniform across threads
    uint32_t k0, k1;
    tf2x32(0u, 42u, 0u, (uint32_t)i, k0, k1);

    // ---- noise (exact JAX threefry normal) ----
    float nz0 = jax_normal_elem(k0, k1, f0);
    float nz1 = jax_normal_elem(k0, k1, f0 + 1u);

    // ---- Euler-Maruyama update ----
    float drift0 = -(gy0 + tilt0);
    float drift1 = -(gy1 + tilt1);
    y0 = y0 + drift0 * dt + SIGMA_C * (nz0 * sqdt);
    y1 = y1 + drift1 * dt + SIGMA_C * (nz1 * sqdt);
    tt += dt;
  }

  out[(size_t)tid * 2 + 0] = y0;
  out[(size_t)tid * 2 + 1] = y1;
}

extern "C" void kernel_launch(void* const* d_in, const int* in_sizes, int n_in,
                              void* d_out, int out_size, void* d_ws,
                              size_t ws_size, hipStream_t stream) {
  const float* x  = (const float*)d_in[0];
  const float* W1 = (const float*)d_in[1];
  const float* b1 = (const float*)d_in[2];
  const float* W2 = (const float*)d_in[3];
  const float* b2 = (const float*)d_in[4];
  const float* W3 = (const float*)d_in[5];
  const float* b3 = (const float*)d_in[6];
  const float* W4 = (const float*)d_in[7];
  const float* b4 = (const float*)d_in[8];
  const float* W5 = (const float*)d_in[9];
  const float* b5 = (const float*)d_in[10];
  const float* Wt = (const float*)d_in[11];
  const float* dt = (const float*)d_in[12];
  const int* nsteps = (const int*)d_in[13];
  float* out = (float*)d_out;

  dim3 grid((BB * NN) / 256);
  dim3 block(256);
  hipLaunchKernelGGL(phinn_kernel, grid, block, 0, stream,
                     x, W1, b1, W2, b2, W3, b3, W4, b4, W5, b5, Wt, dt, nsteps,
                     out);
}